// Round 7
// baseline (27.250 us; speedup 1.0000x reference)
//
#include <hip/hip_runtime.h>

#define NCLS 256
#define NDF  512
#define BSZ  1024
#define ALP  0.1f

// score[b,c] = s1[b,c]-s1[b,t] + 0.5*ALP*(R[t,c]-R[t,t]),  t=gt[b]
//   s1 = df @ fc^T                        (1024x256x512, splitK=8, bf16 MFMA)
//   R[t,c] = sum_d (fc[c,d]^2 - 2 fc[c,d] fc[t,d]) var[t,d]
//            (256x256, 8 dim-chunks of 64, virtual K=128/block, bf16 MFMA)
//   var: faithful per-class sequential recurrence, redundant per R block.
// Two dispatches (kernel boundary = the cheap cross-XCD fence; rounds 4/5 showed
// in-kernel grid barriers cost 25-115us here).
// Round-7: s1 splitK=8 (ONE staging round per block -> halved critical path),
// R blocks first in bid order (longest chain overlaps s1 blocks), LDS union
// (28KB -> 16KB), epilogue folds 8+8.
// MFMA mapping m89/m97-verified and r6-validated (absmax 1.0).

typedef __attribute__((ext_vector_type(8))) short bf16x8;
typedef __attribute__((ext_vector_type(4))) float f32x4;

// pack two fp32 -> one dword of two bf16 (RNE)
__device__ __forceinline__ unsigned rne_pk(float lo, float hi) {
    union { float f; unsigned u; } a, b;
    a.f = lo; b.f = hi;
    unsigned ua = (a.u + 0x7FFFu + ((a.u >> 16) & 1u)) >> 16;
    unsigned ub = (b.u + 0x7FFFu + ((b.u >> 16) & 1u)) & 0xFFFF0000u;
    return ua | ub;
}
// pack 8 fp32 (two float4) -> uint4 of 8 bf16
__device__ __forceinline__ uint4 pk16(float4 p, float4 q) {
    uint4 r;
    r.x = rne_pk(p.x, p.y); r.y = rne_pk(p.z, p.w);
    r.z = rne_pk(q.x, q.y); r.w = rne_pk(q.z, q.w);
    return r;
}

// grid: 640 blocks x 256 threads.
//  bid < 128 : R partial (scheduled first; longest chain).
//              z=bid&7 (64-dim chunk), tile=bid>>3: bm=tile&3, bn=tile>>2.
//  bid >= 128: s1 partial. sid=bid-128; z=sid&7 (K chunk 64), tile=sid>>3:
//              bm=tile&15, bn=tile>>4.
__global__ __launch_bounds__(256) void fused_main(const float* __restrict__ df,
                                                  const int* __restrict__ gt,
                                                  const float* __restrict__ fc,
                                                  float* __restrict__ s1p,
                                                  float* __restrict__ Rp) {
    __shared__ union {
        struct { alignas(16) char A[64 * 128]; alignas(16) char B[64 * 128]; } g;  // bf16 tiles
        struct { int gts[BSZ]; unsigned long long bmap[64 * 16]; } r;              // R pre-pass
    } sm;

    const int tid = threadIdx.x;
    const int bid = blockIdx.x;
    const int lane = tid & 63;
    const int wv = tid >> 6;                 // wave 0..3 -> 32x32 output quadrant
    const int wm = (wv >> 1) * 32, wn = (wv & 1) * 32;
    const int fr = lane & 15;                // frag row/col
    const int fkb = (lane >> 4) * 16;        // frag k byte offset (8 bf16)
    const int fswz = (fr & 7) << 4;          // row&7 == fr&7 (wm/mi offsets are x16)

    // staging mapping: row sr, 16 floats at (tid&3)*16
    const int sr = tid >> 2;
    const int skb = (tid & 3) * 32;          // byte offset of 16 bf16
    const int sswz = (sr & 7) << 4;

    f32x4 acc[2][2];
    acc[0][0] = 0.f; acc[0][1] = 0.f; acc[1][0] = 0.f; acc[1][1] = 0.f;

    auto mma_step = [&](int k0b) {           // one 32-k MFMA step (k0b bytes: 0 or 64)
        const int kb = (k0b + fkb) ^ fswz;
        const bf16x8 aF0 = *(const bf16x8*)(sm.g.A + (wm + fr) * 128 + kb);
        const bf16x8 aF1 = *(const bf16x8*)(sm.g.A + (wm + 16 + fr) * 128 + kb);
        const bf16x8 bF0 = *(const bf16x8*)(sm.g.B + (wn + fr) * 128 + kb);
        const bf16x8 bF1 = *(const bf16x8*)(sm.g.B + (wn + 16 + fr) * 128 + kb);
        acc[0][0] = __builtin_amdgcn_mfma_f32_16x16x32_bf16(aF0, bF0, acc[0][0], 0, 0, 0);
        acc[0][1] = __builtin_amdgcn_mfma_f32_16x16x32_bf16(aF0, bF1, acc[0][1], 0, 0, 0);
        acc[1][0] = __builtin_amdgcn_mfma_f32_16x16x32_bf16(aF1, bF0, acc[1][0], 0, 0, 0);
        acc[1][1] = __builtin_amdgcn_mfma_f32_16x16x32_bf16(aF1, bF1, acc[1][1], 0, 0, 0);
    };
    auto store_tile = [&](float* base) {     // base = tile origin, stride NCLS
#pragma unroll
        for (int mi = 0; mi < 2; ++mi)
#pragma unroll
            for (int ni = 0; ni < 2; ++ni)
#pragma unroll
                for (int r2 = 0; r2 < 4; ++r2)
                    base[(wm + mi * 16 + (lane >> 4) * 4 + r2) * NCLS + wn + ni * 16 + fr] =
                        acc[mi][ni][r2];
    };

    char* arow = sm.g.A + sr * 128;
    char* brow = sm.g.B + sr * 128;

    if (bid >= 128) {
        // ------------------------------- s1 path -------------------------------
        const int sid = bid - 128;
        const int z = sid & 7;               // K chunk of 64
        const int tile = sid >> 3;
        const int bm = tile & 15, bn = tile >> 4;
        const float* Ag = df + (bm * 64 + sr) * NDF + z * 64 + (tid & 3) * 16;
        const float* Bg = fc + (bn * 64 + sr) * NDF + z * 64 + (tid & 3) * 16;

        const float4 a0 = ((const float4*)Ag)[0], a1 = ((const float4*)Ag)[1],
                     a2 = ((const float4*)Ag)[2], a3 = ((const float4*)Ag)[3];
        const float4 b0 = ((const float4*)Bg)[0], b1 = ((const float4*)Bg)[1],
                     b2 = ((const float4*)Bg)[2], b3 = ((const float4*)Bg)[3];
        *(uint4*)(arow + (skb ^ sswz)) = pk16(a0, a1);
        *(uint4*)(arow + ((skb + 16) ^ sswz)) = pk16(a2, a3);
        *(uint4*)(brow + (skb ^ sswz)) = pk16(b0, b1);
        *(uint4*)(brow + ((skb + 16) ^ sswz)) = pk16(b2, b3);
        __syncthreads();
        mma_step(0); mma_step(64);
        store_tile(s1p + z * (BSZ * NCLS) + (bm * 64) * NCLS + bn * 64);
    } else {
        // ------------------------------- R path --------------------------------
        const int z = bid & 7;
        const int tile = bid >> 3;
        const int bm = tile & 3, bn = tile >> 2;
        const int D0 = z * 64;
        const int clocal = sr;                  // class within tile (== staging row)
        const int dg = tid & 3;                 // 16-dim group
        const int myclass = bm * 64 + clocal;
        const int dim0 = D0 + dg * 16;

        // B tile global loads (held in regs across the bmap/var pre-pass)
        const float* Bg = fc + (bn * 64 + sr) * NDF + D0 + (tid & 3) * 16;
        const float4 b0 = ((const float4*)Bg)[0], b1 = ((const float4*)Bg)[1],
                     b2 = ((const float4*)Bg)[2], b3 = ((const float4*)Bg)[3];

        for (int i = tid; i < BSZ; i += 256) sm.r.gts[i] = gt[i];
        for (int i = tid; i < 1024; i += 256) sm.r.bmap[i] = 0ull;
        __syncthreads();
        // order-preserving per-class sample bitmap (64 classes x 1024 bits)
        for (int i = tid; i < BSZ; i += 256) {
            const int c = sm.r.gts[i] - bm * 64;
            if ((unsigned)c < 64u) atomicOr(&sm.r.bmap[c * 16 + (i >> 6)], 1ull << (i & 63));
        }
        const float* fct = fc + myclass * NDF + dim0;
        float fcq[16];
        {
            const float4 q0 = ((const float4*)fct)[0], q1 = ((const float4*)fct)[1];
            const float4 q2 = ((const float4*)fct)[2], q3 = ((const float4*)fct)[3];
            fcq[0]=q0.x; fcq[1]=q0.y; fcq[2]=q0.z; fcq[3]=q0.w;
            fcq[4]=q1.x; fcq[5]=q1.y; fcq[6]=q1.z; fcq[7]=q1.w;
            fcq[8]=q2.x; fcq[9]=q2.y; fcq[10]=q2.z; fcq[11]=q2.w;
            fcq[12]=q3.x; fcq[13]=q3.y; fcq[14]=q3.z; fcq[15]=q3.w;
        }
        __syncthreads();

        // sequential running-var recurrence for (myclass, dims dim0..dim0+16)
        float m[16], v[16];
#pragma unroll
        for (int j = 0; j < 16; ++j) { m[j] = 0.f; v[j] = 0.f; }
        float nf = 0.f;
        {
            int w = 0;
            unsigned long long bits = sm.r.bmap[clocal * 16];
            auto next = [&]() -> int {
                while (bits == 0ull) {
                    if (w >= 15) return -1;
                    bits = sm.r.bmap[clocal * 16 + (++w)];
                }
                const int b = __ffsll((unsigned long long)bits) - 1;
                bits &= bits - 1ull;
                return (w << 6) + b;
            };
            int cur = next();
            float f[16];
            if (cur >= 0) {
                const float* p = df + cur * NDF + dim0;
                const float4 q0 = ((const float4*)p)[0], q1 = ((const float4*)p)[1];
                const float4 q2 = ((const float4*)p)[2], q3 = ((const float4*)p)[3];
                f[0]=q0.x; f[1]=q0.y; f[2]=q0.z; f[3]=q0.w;
                f[4]=q1.x; f[5]=q1.y; f[6]=q1.z; f[7]=q1.w;
                f[8]=q2.x; f[9]=q2.y; f[10]=q2.z; f[11]=q2.w;
                f[12]=q3.x; f[13]=q3.y; f[14]=q3.z; f[15]=q3.w;
            }
            while (cur >= 0) {
                const int nxt = next();
                float g[16];
                if (nxt >= 0) {   // prefetch next sample before the dependent update
                    const float* p = df + nxt * NDF + dim0;
                    const float4 q0 = ((const float4*)p)[0], q1 = ((const float4*)p)[1];
                    const float4 q2 = ((const float4*)p)[2], q3 = ((const float4*)p)[3];
                    g[0]=q0.x; g[1]=q0.y; g[2]=q0.z; g[3]=q0.w;
                    g[4]=q1.x; g[5]=q1.y; g[6]=q1.z; g[7]=q1.w;
                    g[8]=q2.x; g[9]=q2.y; g[10]=q2.z; g[11]=q2.w;
                    g[12]=q3.x; g[13]=q3.y; g[14]=q3.z; g[15]=q3.w;
                }
                const float c2 = 1.0f / (nf + 1.0f);
                const float c1 = nf * c2;
                const float c12 = c1 * c2;
#pragma unroll
                for (int j = 0; j < 16; ++j) {
                    m[j] = m[j] * c1 + f[j] * c2;     // == f when nf==0
                    const float a = f[j] - m[j];
                    v[j] = v[j] * c1 + a * a * c12;
                }
                nf += 1.0f;
#pragma unroll
                for (int j = 0; j < 16; ++j) f[j] = g[j];
                cur = nxt;
            }
        }
        __syncthreads();   // bmap reads done before staging overwrites (LDS union!)

        // virtual ks0 (linear): A = -2*fc_t*var (from regs), B = fc
        {
            float4 p0, p1, p2, p3;
            p0.x=-2.f*fcq[0]*v[0];  p0.y=-2.f*fcq[1]*v[1];  p0.z=-2.f*fcq[2]*v[2];  p0.w=-2.f*fcq[3]*v[3];
            p1.x=-2.f*fcq[4]*v[4];  p1.y=-2.f*fcq[5]*v[5];  p1.z=-2.f*fcq[6]*v[6];  p1.w=-2.f*fcq[7]*v[7];
            p2.x=-2.f*fcq[8]*v[8];  p2.y=-2.f*fcq[9]*v[9];  p2.z=-2.f*fcq[10]*v[10]; p2.w=-2.f*fcq[11]*v[11];
            p3.x=-2.f*fcq[12]*v[12]; p3.y=-2.f*fcq[13]*v[13]; p3.z=-2.f*fcq[14]*v[14]; p3.w=-2.f*fcq[15]*v[15];
            *(uint4*)(arow + (skb ^ sswz)) = pk16(p0, p1);
            *(uint4*)(arow + ((skb + 16) ^ sswz)) = pk16(p2, p3);
            *(uint4*)(brow + (skb ^ sswz)) = pk16(b0, b1);
            *(uint4*)(brow + ((skb + 16) ^ sswz)) = pk16(b2, b3);
        }
        __syncthreads();
        mma_step(0); mma_step(64);
        __syncthreads();
        // virtual ks1 (quadratic): A = var, B = fc^2
        {
            float4 p0, p1, p2, p3, s0, s1, s2, s3;
            p0.x=v[0];  p0.y=v[1];  p0.z=v[2];  p0.w=v[3];
            p1.x=v[4];  p1.y=v[5];  p1.z=v[6];  p1.w=v[7];
            p2.x=v[8];  p2.y=v[9];  p2.z=v[10]; p2.w=v[11];
            p3.x=v[12]; p3.y=v[13]; p3.z=v[14]; p3.w=v[15];
            s0.x=b0.x*b0.x; s0.y=b0.y*b0.y; s0.z=b0.z*b0.z; s0.w=b0.w*b0.w;
            s1.x=b1.x*b1.x; s1.y=b1.y*b1.y; s1.z=b1.z*b1.z; s1.w=b1.w*b1.w;
            s2.x=b2.x*b2.x; s2.y=b2.y*b2.y; s2.z=b2.z*b2.z; s2.w=b2.w*b2.w;
            s3.x=b3.x*b3.x; s3.y=b3.y*b3.y; s3.z=b3.z*b3.z; s3.w=b3.w*b3.w;
            *(uint4*)(arow + (skb ^ sswz)) = pk16(p0, p1);
            *(uint4*)(arow + ((skb + 16) ^ sswz)) = pk16(p2, p3);
            *(uint4*)(brow + (skb ^ sswz)) = pk16(s0, s1);
            *(uint4*)(brow + ((skb + 16) ^ sswz)) = pk16(s2, s3);
        }
        __syncthreads();
        mma_step(0); mma_step(64);
        store_tile(Rp + z * (NCLS * NCLS) + (bm * 64) * NCLS + bn * 64);
    }
}

// ---------------------------------------------------------------------------
// Epilogue: fold 8 s1 + 8 R partials; out[b,c]=(v1-v1[t]) + 0.05*(vR-vR[t]).
// 256 blocks x 256 thr: wave w handles row b=bid*4+w (wave-uniform t), float4 cols.
__global__ __launch_bounds__(256) void epilogue_kernel(const float* __restrict__ s1p,
                                                       const float* __restrict__ Rp,
                                                       const int* __restrict__ gt,
                                                       float* __restrict__ out) {
    const int b = blockIdx.x * 4 + (threadIdx.x >> 6);
    const int cq = (threadIdx.x & 63) * 4;
    const int t = gt[b];
    float4 v1 = make_float4(0.f, 0.f, 0.f, 0.f);
    float v1t = 0.f;
#pragma unroll
    for (int zz = 0; zz < 8; ++zz) {
        const float* row = s1p + zz * (BSZ * NCLS) + b * NCLS;
        const float4 q = *(const float4*)(row + cq);
        v1.x += q.x; v1.y += q.y; v1.z += q.z; v1.w += q.w;
        v1t += row[t];
    }
    float4 vR = make_float4(0.f, 0.f, 0.f, 0.f);
    float vRt = 0.f;
#pragma unroll
    for (int zz = 0; zz < 8; ++zz) {
        const float* row = Rp + zz * (NCLS * NCLS) + t * NCLS;
        const float4 q = *(const float4*)(row + cq);
        vR.x += q.x; vR.y += q.y; vR.z += q.z; vR.w += q.w;
        vRt += row[t];
    }
    float4 o;
    o.x = (v1.x - v1t) + 0.5f * ALP * (vR.x - vRt);
    o.y = (v1.y - v1t) + 0.5f * ALP * (vR.y - vRt);
    o.z = (v1.z - v1t) + 0.5f * ALP * (vR.z - vRt);
    o.w = (v1.w - v1t) + 0.5f * ALP * (vR.w - vRt);
    *(float4*)(out + b * NCLS + cq) = o;
}

// ---------------------------------------------------------------------------
extern "C" void kernel_launch(void* const* d_in, const int* in_sizes, int n_in,
                              void* d_out, int out_size, void* d_ws, size_t ws_size,
                              hipStream_t stream) {
    const float* df = (const float*)d_in[0];
    const int* gt = (const int*)d_in[1];
    const float* fc = (const float*)d_in[2];
    float* out = (float*)d_out;

    float* ws = (float*)d_ws;
    float* s1p = ws;                           // 8*BSZ*NCLS  = 2,097,152 f (8 MB)
    float* Rp = s1p + 8 * BSZ * NCLS;          // 8*NCLS*NCLS =   524,288 f (2 MB)

    fused_main<<<640, 256, 0, stream>>>(df, gt, fc, s1p, Rp);
    epilogue_kernel<<<256, 256, 0, stream>>>(s1p, Rp, gt, out);
}

// Round 8
// 25.922 us; speedup vs baseline: 1.0512x; 1.0512x over previous
//
#include <hip/hip_runtime.h>

#define NCLS 256
#define NDF  512
#define BSZ  1024
#define ALP  0.1f

// score[b,c] = s1[b,c]-s1[b,t] + 0.5*ALP*(R[t,c]-R[t,t]),  t=gt[b]
//   s1 = df @ fc^T                        (1024x256x512, splitK=4, bf16 MFMA)
//   R[t,c] = sum_d (fc[c,d]^2 - 2 fc[c,d] fc[t,d]) var[t,d]
//            (256x256, 8 dim-chunks of 64 -> virtual K=128 per block, bf16 MFMA)
//   var: faithful per-class sequential recurrence, redundant per R block.
// Two dispatches (kernel boundary = the cheap cross-XCD fence; rounds 4/5 showed
// in-kernel grid barriers cost 25-115us here via L2 maintenance / uncached traffic).
// Round-8: ONE staging round per block for BOTH paths (s1: K-chunk 128 at
// splitK=4, R: linear+quad packed side-by-side in one virtual-K=128 tile);
// splitK stays 4 (R7 showed splitK=8's extra partial traffic costs more than
// the staging round it saves). R blocks first (longest chain), LDS union.
// MFMA mapping m89/m97-verified, r6/r7-validated (absmax 1.0).

typedef __attribute__((ext_vector_type(8))) short bf16x8;
typedef __attribute__((ext_vector_type(4))) float f32x4;

// pack two fp32 -> one dword of two bf16 (RNE)
__device__ __forceinline__ unsigned rne_pk(float lo, float hi) {
    union { float f; unsigned u; } a, b;
    a.f = lo; b.f = hi;
    unsigned ua = (a.u + 0x7FFFu + ((a.u >> 16) & 1u)) >> 16;
    unsigned ub = (b.u + 0x7FFFu + ((b.u >> 16) & 1u)) & 0xFFFF0000u;
    return ua | ub;
}
// pack 8 fp32 (two float4) -> uint4 of 8 bf16
__device__ __forceinline__ uint4 pk16(float4 p, float4 q) {
    uint4 r;
    r.x = rne_pk(p.x, p.y); r.y = rne_pk(p.z, p.w);
    r.z = rne_pk(q.x, q.y); r.w = rne_pk(q.z, q.w);
    return r;
}

// grid: 384 blocks x 256 threads.
//  bid < 128 : R partial (first; longest chain).
//              z=bid&7 (64-dim chunk), tile=bid>>3: bm=tile&3, bn=tile>>2.
//  bid >= 128: s1 partial. sid=bid-128; z=sid&3 (K chunk 128), tile=sid>>2:
//              bm=tile&15, bn=tile>>4.
__global__ __launch_bounds__(256) void fused_main(const float* __restrict__ df,
                                                  const int* __restrict__ gt,
                                                  const float* __restrict__ fc,
                                                  float* __restrict__ s1p,
                                                  float* __restrict__ Rp) {
    __shared__ union {
        struct { alignas(16) char A[64 * 256]; alignas(16) char B[64 * 256]; } g;  // 64 x 128 bf16
        struct { int gts[BSZ]; unsigned long long bmap[64 * 16]; } r;              // R pre-pass
    } sm;

    const int tid = threadIdx.x;
    const int bid = blockIdx.x;
    const int lane = tid & 63;
    const int wv = tid >> 6;                 // wave 0..3 -> 32x32 output quadrant
    const int wm = (wv >> 1) * 32, wn = (wv & 1) * 32;
    const int fr = lane & 15;                // frag row/col
    const int fkb = (lane >> 4) * 16;        // frag k byte offset (8 bf16)
    const int fswz = (fr & 7) << 4;          // row&7 == fr&7 (wm/mi offsets are x16)

    // staging mapping: row sr = tid>>2, 32 floats (64 bytes bf16) at (tid&3)*64
    const int sr = tid >> 2;
    const int sswz = (sr & 7) << 4;
    char* arow = sm.g.A + sr * 256;
    char* brow = sm.g.B + sr * 256;

    f32x4 acc[2][2];
    acc[0][0] = 0.f; acc[0][1] = 0.f; acc[1][0] = 0.f; acc[1][1] = 0.f;

    auto mma_step = [&](int k0b) {           // one 32-k MFMA step (k0b bytes: 0/64/128/192)
        const int kb = (k0b + fkb) ^ fswz;
        const bf16x8 aF0 = *(const bf16x8*)(sm.g.A + (wm + fr) * 256 + kb);
        const bf16x8 aF1 = *(const bf16x8*)(sm.g.A + (wm + 16 + fr) * 256 + kb);
        const bf16x8 bF0 = *(const bf16x8*)(sm.g.B + (wn + fr) * 256 + kb);
        const bf16x8 bF1 = *(const bf16x8*)(sm.g.B + (wn + 16 + fr) * 256 + kb);
        acc[0][0] = __builtin_amdgcn_mfma_f32_16x16x32_bf16(aF0, bF0, acc[0][0], 0, 0, 0);
        acc[0][1] = __builtin_amdgcn_mfma_f32_16x16x32_bf16(aF0, bF1, acc[0][1], 0, 0, 0);
        acc[1][0] = __builtin_amdgcn_mfma_f32_16x16x32_bf16(aF1, bF0, acc[1][0], 0, 0, 0);
        acc[1][1] = __builtin_amdgcn_mfma_f32_16x16x32_bf16(aF1, bF1, acc[1][1], 0, 0, 0);
    };
    auto store_tile = [&](float* base) {     // base = tile origin, stride NCLS
#pragma unroll
        for (int mi = 0; mi < 2; ++mi)
#pragma unroll
            for (int ni = 0; ni < 2; ++ni)
#pragma unroll
                for (int r2 = 0; r2 < 4; ++r2)
                    base[(wm + mi * 16 + (lane >> 4) * 4 + r2) * NCLS + wn + ni * 16 + fr] =
                        acc[mi][ni][r2];
    };

    if (bid >= 128) {
        // ------------------------------- s1 path -------------------------------
        const int sid = bid - 128;
        const int z = sid & 3;               // K chunk of 128
        const int tile = sid >> 2;
        const int bm = tile & 15, bn = tile >> 4;
        const float* Ag = df + (bm * 64 + sr) * NDF + z * 128 + (tid & 3) * 32;
        const float* Bg = fc + (bn * 64 + sr) * NDF + z * 128 + (tid & 3) * 32;
        const int kbase = (tid & 3) * 64;    // byte base of this thread's 32 bf16

        float4 a[8], b[8];
#pragma unroll
        for (int i = 0; i < 8; ++i) a[i] = ((const float4*)Ag)[i];
#pragma unroll
        for (int i = 0; i < 8; ++i) b[i] = ((const float4*)Bg)[i];
        *(uint4*)(arow + ((kbase + 0) ^ sswz)) = pk16(a[0], a[1]);
        *(uint4*)(arow + ((kbase + 16) ^ sswz)) = pk16(a[2], a[3]);
        *(uint4*)(arow + ((kbase + 32) ^ sswz)) = pk16(a[4], a[5]);
        *(uint4*)(arow + ((kbase + 48) ^ sswz)) = pk16(a[6], a[7]);
        *(uint4*)(brow + ((kbase + 0) ^ sswz)) = pk16(b[0], b[1]);
        *(uint4*)(brow + ((kbase + 16) ^ sswz)) = pk16(b[2], b[3]);
        *(uint4*)(brow + ((kbase + 32) ^ sswz)) = pk16(b[4], b[5]);
        *(uint4*)(brow + ((kbase + 48) ^ sswz)) = pk16(b[6], b[7]);
        __syncthreads();
        mma_step(0); mma_step(64); mma_step(128); mma_step(192);
        store_tile(s1p + z * (BSZ * NCLS) + (bm * 64) * NCLS + bn * 64);
    } else {
        // ------------------------------- R path --------------------------------
        // Virtual K=128 tile: cols 0-63 linear (A=-2*fc_t*var, B=fc),
        //                     cols 64-127 quadratic (A=var, B=fc^2).
        const int z = bid & 7;
        const int tile = bid >> 3;
        const int bm = tile & 3, bn = tile >> 2;
        const int D0 = z * 64;
        const int clocal = sr;                  // class within tile (== staging row)
        const int myclass = bm * 64 + clocal;
        const int dim0 = D0 + (tid & 3) * 16;   // this thread's 16-dim group
        const int kbl = (tid & 3) * 32;         // linear byte base (16 bf16)
        const int kbq = 128 + kbl;              // quadratic byte base

        // B tile global loads (held in regs across the bmap/var pre-pass)
        const float* Bg = fc + (bn * 64 + sr) * NDF + dim0;
        const float4 b0 = ((const float4*)Bg)[0], b1 = ((const float4*)Bg)[1],
                     b2 = ((const float4*)Bg)[2], b3 = ((const float4*)Bg)[3];

        for (int i = tid; i < BSZ; i += 256) sm.r.gts[i] = gt[i];
        for (int i = tid; i < 1024; i += 256) sm.r.bmap[i] = 0ull;
        __syncthreads();
        // order-preserving per-class sample bitmap (64 classes x 1024 bits)
        for (int i = tid; i < BSZ; i += 256) {
            const int c = sm.r.gts[i] - bm * 64;
            if ((unsigned)c < 64u) atomicOr(&sm.r.bmap[c * 16 + (i >> 6)], 1ull << (i & 63));
        }
        const float* fct = fc + myclass * NDF + dim0;
        float fcq[16];
        {
            const float4 q0 = ((const float4*)fct)[0], q1 = ((const float4*)fct)[1];
            const float4 q2 = ((const float4*)fct)[2], q3 = ((const float4*)fct)[3];
            fcq[0]=q0.x; fcq[1]=q0.y; fcq[2]=q0.z; fcq[3]=q0.w;
            fcq[4]=q1.x; fcq[5]=q1.y; fcq[6]=q1.z; fcq[7]=q1.w;
            fcq[8]=q2.x; fcq[9]=q2.y; fcq[10]=q2.z; fcq[11]=q2.w;
            fcq[12]=q3.x; fcq[13]=q3.y; fcq[14]=q3.z; fcq[15]=q3.w;
        }
        __syncthreads();

        // sequential running-var recurrence for (myclass, dims dim0..dim0+16)
        float m[16], v[16];
#pragma unroll
        for (int j = 0; j < 16; ++j) { m[j] = 0.f; v[j] = 0.f; }
        float nf = 0.f;
        {
            int w = 0;
            unsigned long long bits = sm.r.bmap[clocal * 16];
            auto next = [&]() -> int {
                while (bits == 0ull) {
                    if (w >= 15) return -1;
                    bits = sm.r.bmap[clocal * 16 + (++w)];
                }
                const int b = __ffsll((unsigned long long)bits) - 1;
                bits &= bits - 1ull;
                return (w << 6) + b;
            };
            int cur = next();
            float f[16];
            if (cur >= 0) {
                const float* p = df + cur * NDF + dim0;
                const float4 q0 = ((const float4*)p)[0], q1 = ((const float4*)p)[1];
                const float4 q2 = ((const float4*)p)[2], q3 = ((const float4*)p)[3];
                f[0]=q0.x; f[1]=q0.y; f[2]=q0.z; f[3]=q0.w;
                f[4]=q1.x; f[5]=q1.y; f[6]=q1.z; f[7]=q1.w;
                f[8]=q2.x; f[9]=q2.y; f[10]=q2.z; f[11]=q2.w;
                f[12]=q3.x; f[13]=q3.y; f[14]=q3.z; f[15]=q3.w;
            }
            while (cur >= 0) {
                const int nxt = next();
                float g[16];
                if (nxt >= 0) {   // prefetch next sample before the dependent update
                    const float* p = df + nxt * NDF + dim0;
                    const float4 q0 = ((const float4*)p)[0], q1 = ((const float4*)p)[1];
                    const float4 q2 = ((const float4*)p)[2], q3 = ((const float4*)p)[3];
                    g[0]=q0.x; g[1]=q0.y; g[2]=q0.z; g[3]=q0.w;
                    g[4]=q1.x; g[5]=q1.y; g[6]=q1.z; g[7]=q1.w;
                    g[8]=q2.x; g[9]=q2.y; g[10]=q2.z; g[11]=q2.w;
                    g[12]=q3.x; g[13]=q3.y; g[14]=q3.z; g[15]=q3.w;
                }
                const float c2 = 1.0f / (nf + 1.0f);
                const float c1 = nf * c2;
                const float c12 = c1 * c2;
#pragma unroll
                for (int j = 0; j < 16; ++j) {
                    m[j] = m[j] * c1 + f[j] * c2;     // == f when nf==0
                    const float a = f[j] - m[j];
                    v[j] = v[j] * c1 + a * a * c12;
                }
                nf += 1.0f;
#pragma unroll
                for (int j = 0; j < 16; ++j) f[j] = g[j];
                cur = nxt;
            }
        }
        __syncthreads();   // bmap reads done before staging overwrites (LDS union!)

        // single staging round: linear cols + quadratic cols
        {
            float4 l0, l1, l2, l3;
            l0.x=-2.f*fcq[0]*v[0];  l0.y=-2.f*fcq[1]*v[1];  l0.z=-2.f*fcq[2]*v[2];  l0.w=-2.f*fcq[3]*v[3];
            l1.x=-2.f*fcq[4]*v[4];  l1.y=-2.f*fcq[5]*v[5];  l1.z=-2.f*fcq[6]*v[6];  l1.w=-2.f*fcq[7]*v[7];
            l2.x=-2.f*fcq[8]*v[8];  l2.y=-2.f*fcq[9]*v[9];  l2.z=-2.f*fcq[10]*v[10]; l2.w=-2.f*fcq[11]*v[11];
            l3.x=-2.f*fcq[12]*v[12]; l3.y=-2.f*fcq[13]*v[13]; l3.z=-2.f*fcq[14]*v[14]; l3.w=-2.f*fcq[15]*v[15];
            float4 p0, p1, p2, p3;
            p0.x=v[0];  p0.y=v[1];  p0.z=v[2];  p0.w=v[3];
            p1.x=v[4];  p1.y=v[5];  p1.z=v[6];  p1.w=v[7];
            p2.x=v[8];  p2.y=v[9];  p2.z=v[10]; p2.w=v[11];
            p3.x=v[12]; p3.y=v[13]; p3.z=v[14]; p3.w=v[15];
            float4 s0, s1, s2, s3;
            s0.x=b0.x*b0.x; s0.y=b0.y*b0.y; s0.z=b0.z*b0.z; s0.w=b0.w*b0.w;
            s1.x=b1.x*b1.x; s1.y=b1.y*b1.y; s1.z=b1.z*b1.z; s1.w=b1.w*b1.w;
            s2.x=b2.x*b2.x; s2.y=b2.y*b2.y; s2.z=b2.z*b2.z; s2.w=b2.w*b2.w;
            s3.x=b3.x*b3.x; s3.y=b3.y*b3.y; s3.z=b3.z*b3.z; s3.w=b3.w*b3.w;
            *(uint4*)(arow + ((kbl + 0) ^ sswz)) = pk16(l0, l1);
            *(uint4*)(arow + ((kbl + 16) ^ sswz)) = pk16(l2, l3);
            *(uint4*)(arow + ((kbq + 0) ^ sswz)) = pk16(p0, p1);
            *(uint4*)(arow + ((kbq + 16) ^ sswz)) = pk16(p2, p3);
            *(uint4*)(brow + ((kbl + 0) ^ sswz)) = pk16(b0, b1);
            *(uint4*)(brow + ((kbl + 16) ^ sswz)) = pk16(b2, b3);
            *(uint4*)(brow + ((kbq + 0) ^ sswz)) = pk16(s0, s1);
            *(uint4*)(brow + ((kbq + 16) ^ sswz)) = pk16(s2, s3);
        }
        __syncthreads();
        mma_step(0); mma_step(64); mma_step(128); mma_step(192);
        store_tile(Rp + z * (NCLS * NCLS) + (bm * 64) * NCLS + bn * 64);
    }
}

// ---------------------------------------------------------------------------
// Epilogue: fold 4 s1 + 8 R partials; out[b,c]=(v1-v1[t]) + 0.05*(vR-vR[t]).
// 256 blocks x 256 thr: wave w handles row b=bid*4+w (wave-uniform t), float4 cols.
__global__ __launch_bounds__(256) void epilogue_kernel(const float* __restrict__ s1p,
                                                       const float* __restrict__ Rp,
                                                       const int* __restrict__ gt,
                                                       float* __restrict__ out) {
    const int b = blockIdx.x * 4 + (threadIdx.x >> 6);
    const int cq = (threadIdx.x & 63) * 4;
    const int t = gt[b];
    float4 v1 = make_float4(0.f, 0.f, 0.f, 0.f);
    float v1t = 0.f;
#pragma unroll
    for (int zz = 0; zz < 4; ++zz) {
        const float* row = s1p + zz * (BSZ * NCLS) + b * NCLS;
        const float4 q = *(const float4*)(row + cq);
        v1.x += q.x; v1.y += q.y; v1.z += q.z; v1.w += q.w;
        v1t += row[t];
    }
    float4 vR = make_float4(0.f, 0.f, 0.f, 0.f);
    float vRt = 0.f;
#pragma unroll
    for (int zz = 0; zz < 8; ++zz) {
        const float* row = Rp + zz * (NCLS * NCLS) + t * NCLS;
        const float4 q = *(const float4*)(row + cq);
        vR.x += q.x; vR.y += q.y; vR.z += q.z; vR.w += q.w;
        vRt += row[t];
    }
    float4 o;
    o.x = (v1.x - v1t) + 0.5f * ALP * (vR.x - vRt);
    o.y = (v1.y - v1t) + 0.5f * ALP * (vR.y - vRt);
    o.z = (v1.z - v1t) + 0.5f * ALP * (vR.z - vRt);
    o.w = (v1.w - v1t) + 0.5f * ALP * (vR.w - vRt);
    *(float4*)(out + b * NCLS + cq) = o;
}

// ---------------------------------------------------------------------------
extern "C" void kernel_launch(void* const* d_in, const int* in_sizes, int n_in,
                              void* d_out, int out_size, void* d_ws, size_t ws_size,
                              hipStream_t stream) {
    const float* df = (const float*)d_in[0];
    const int* gt = (const int*)d_in[1];
    const float* fc = (const float*)d_in[2];
    float* out = (float*)d_out;

    float* ws = (float*)d_ws;
    float* s1p = ws;                           // 4*BSZ*NCLS  = 1,048,576 f (4 MB)
    float* Rp = s1p + 4 * BSZ * NCLS;          // 8*NCLS*NCLS =   524,288 f (2 MB)

    fused_main<<<384, 256, 0, stream>>>(df, gt, fc, s1p, Rp);
    epilogue_kernel<<<256, 256, 0, stream>>>(s1p, Rp, gt, out);
}

// Round 9
// 24.867 us; speedup vs baseline: 1.0958x; 1.0424x over previous
//
#include <hip/hip_runtime.h>

#define NCLS 256
#define NDF  512
#define BSZ  1024
#define ALP  0.1f

// score[b,c] = s1[b,c]-s1[b,t] + 0.5*ALP*(R[t,c]-R[t,t]),  t=gt[b]
//   K1: R partials (8 dim-chunks, bf16 MFMA, R8-validated path)  +
//       bias1[b] = s1[b,t] via one wave/sample bf16-rounded dot (matches MFMA
//       operand rounding -> out[b,t] ~ 0).
//   K2: full-K (512) 32x32-tile s1 GEMM, ONE staging round (64KB LDS), epilogue
//       fused: fold 8 R slabs + bias subtract -> writes out directly.
// No s1 partials, no third dispatch, no atomics (deterministic).
// MFMA mapping m89/m97-verified, r6/r7/r8-validated (absmax 1.0).

typedef __attribute__((ext_vector_type(8))) short bf16x8;
typedef __attribute__((ext_vector_type(4))) float f32x4;

// RNE fp32->bf16 (bits), matching MFMA operand rounding everywhere.
__device__ __forceinline__ unsigned rne_pk(float lo, float hi) {
    union { float f; unsigned u; } a, b;
    a.f = lo; b.f = hi;
    unsigned ua = (a.u + 0x7FFFu + ((a.u >> 16) & 1u)) >> 16;
    unsigned ub = (b.u + 0x7FFFu + ((b.u >> 16) & 1u)) & 0xFFFF0000u;
    return ua | ub;
}
__device__ __forceinline__ uint4 pk16(float4 p, float4 q) {
    uint4 r;
    r.x = rne_pk(p.x, p.y); r.y = rne_pk(p.z, p.w);
    r.z = rne_pk(q.x, q.y); r.w = rne_pk(q.z, q.w);
    return r;
}
__device__ __forceinline__ float bf16r(float x) {   // same RNE, back to fp32
    union { float f; unsigned u; } c; c.f = x;
    c.u = (c.u + 0x7FFFu + ((c.u >> 16) & 1u)) & 0xFFFF0000u;
    return c.f;
}

// ---------------------------------------------------------------------------
// Kernel 1: grid 384 x 256.
//  bid < 128 : R partial (R8-validated). z=bid&7 (64-dim chunk), tile=bid>>3:
//              bm=tile&3, bn=tile>>2. Virtual K=128 (linear cols 0-63 | quad 64-127).
//  bid >= 128: bias1. wave w of block q computes bias1[q*4+w].
__global__ __launch_bounds__(256) void k1_R_bias(const float* __restrict__ df,
                                                 const int* __restrict__ gt,
                                                 const float* __restrict__ fc,
                                                 float* __restrict__ Rp,
                                                 float* __restrict__ bias1) {
    __shared__ union {
        struct { alignas(16) char A[64 * 256]; alignas(16) char B[64 * 256]; } g;  // 64x128 bf16
        struct { int gts[BSZ]; unsigned long long bmap[64 * 16]; } r;
    } sm;

    const int tid = threadIdx.x;
    const int bid = blockIdx.x;
    const int lane = tid & 63;

    if (bid >= 128) {
        // ----------------------------- bias1 path ------------------------------
        const int b = (bid - 128) * 4 + (tid >> 6);
        const int t = gt[b];                       // wave-uniform broadcast
        const float* pd = df + b * NDF + lane * 8;
        const float* pf = fc + t * NDF + lane * 8;
        const float4 d0 = ((const float4*)pd)[0], d1 = ((const float4*)pd)[1];
        const float4 f0 = ((const float4*)pf)[0], f1 = ((const float4*)pf)[1];
        float s = 0.f;
        s = fmaf(bf16r(d0.x), bf16r(f0.x), s); s = fmaf(bf16r(d0.y), bf16r(f0.y), s);
        s = fmaf(bf16r(d0.z), bf16r(f0.z), s); s = fmaf(bf16r(d0.w), bf16r(f0.w), s);
        s = fmaf(bf16r(d1.x), bf16r(f1.x), s); s = fmaf(bf16r(d1.y), bf16r(f1.y), s);
        s = fmaf(bf16r(d1.z), bf16r(f1.z), s); s = fmaf(bf16r(d1.w), bf16r(f1.w), s);
#pragma unroll
        for (int off = 32; off; off >>= 1) s += __shfl_xor(s, off, 64);
        if (lane == 0) bias1[b] = s;
        return;
    }

    // ------------------------------- R path ------------------------------------
    const int wv = tid >> 6;
    const int wm = (wv >> 1) * 32, wn = (wv & 1) * 32;
    const int fr = lane & 15;
    const int fkb = (lane >> 4) * 16;
    const int fswz = (fr & 7) << 4;

    const int sr = tid >> 2;
    const int sswz = (sr & 7) << 4;
    char* arow = sm.g.A + sr * 256;
    char* brow = sm.g.B + sr * 256;

    f32x4 acc[2][2];
    acc[0][0] = 0.f; acc[0][1] = 0.f; acc[1][0] = 0.f; acc[1][1] = 0.f;

    auto mma_step = [&](int k0b) {
        const int kb = (k0b + fkb) ^ fswz;
        const bf16x8 aF0 = *(const bf16x8*)(sm.g.A + (wm + fr) * 256 + kb);
        const bf16x8 aF1 = *(const bf16x8*)(sm.g.A + (wm + 16 + fr) * 256 + kb);
        const bf16x8 bF0 = *(const bf16x8*)(sm.g.B + (wn + fr) * 256 + kb);
        const bf16x8 bF1 = *(const bf16x8*)(sm.g.B + (wn + 16 + fr) * 256 + kb);
        acc[0][0] = __builtin_amdgcn_mfma_f32_16x16x32_bf16(aF0, bF0, acc[0][0], 0, 0, 0);
        acc[0][1] = __builtin_amdgcn_mfma_f32_16x16x32_bf16(aF0, bF1, acc[0][1], 0, 0, 0);
        acc[1][0] = __builtin_amdgcn_mfma_f32_16x16x32_bf16(aF1, bF0, acc[1][0], 0, 0, 0);
        acc[1][1] = __builtin_amdgcn_mfma_f32_16x16x32_bf16(aF1, bF1, acc[1][1], 0, 0, 0);
    };

    const int z = bid & 7;
    const int tile = bid >> 3;
    const int bm = tile & 3, bn = tile >> 2;
    const int D0 = z * 64;
    const int clocal = sr;
    const int myclass = bm * 64 + clocal;
    const int dim0 = D0 + (tid & 3) * 16;
    const int kbl = (tid & 3) * 32;
    const int kbq = 128 + kbl;

    const float* Bg = fc + (bn * 64 + sr) * NDF + dim0;
    const float4 b0 = ((const float4*)Bg)[0], b1 = ((const float4*)Bg)[1],
                 b2 = ((const float4*)Bg)[2], b3 = ((const float4*)Bg)[3];

    for (int i = tid; i < BSZ; i += 256) sm.r.gts[i] = gt[i];
    for (int i = tid; i < 1024; i += 256) sm.r.bmap[i] = 0ull;
    __syncthreads();
    for (int i = tid; i < BSZ; i += 256) {
        const int c = sm.r.gts[i] - bm * 64;
        if ((unsigned)c < 64u) atomicOr(&sm.r.bmap[c * 16 + (i >> 6)], 1ull << (i & 63));
    }
    const float* fct = fc + myclass * NDF + dim0;
    float fcq[16];
    {
        const float4 q0 = ((const float4*)fct)[0], q1 = ((const float4*)fct)[1];
        const float4 q2 = ((const float4*)fct)[2], q3 = ((const float4*)fct)[3];
        fcq[0]=q0.x; fcq[1]=q0.y; fcq[2]=q0.z; fcq[3]=q0.w;
        fcq[4]=q1.x; fcq[5]=q1.y; fcq[6]=q1.z; fcq[7]=q1.w;
        fcq[8]=q2.x; fcq[9]=q2.y; fcq[10]=q2.z; fcq[11]=q2.w;
        fcq[12]=q3.x; fcq[13]=q3.y; fcq[14]=q3.z; fcq[15]=q3.w;
    }
    __syncthreads();

    // sequential running-var recurrence for (myclass, dims dim0..dim0+16)
    float m[16], v[16];
#pragma unroll
    for (int j = 0; j < 16; ++j) { m[j] = 0.f; v[j] = 0.f; }
    float nf = 0.f;
    {
        int w = 0;
        unsigned long long bits = sm.r.bmap[clocal * 16];
        auto next = [&]() -> int {
            while (bits == 0ull) {
                if (w >= 15) return -1;
                bits = sm.r.bmap[clocal * 16 + (++w)];
            }
            const int b = __ffsll((unsigned long long)bits) - 1;
            bits &= bits - 1ull;
            return (w << 6) + b;
        };
        int cur = next();
        float f[16];
        if (cur >= 0) {
            const float* p = df + cur * NDF + dim0;
            const float4 q0 = ((const float4*)p)[0], q1 = ((const float4*)p)[1];
            const float4 q2 = ((const float4*)p)[2], q3 = ((const float4*)p)[3];
            f[0]=q0.x; f[1]=q0.y; f[2]=q0.z; f[3]=q0.w;
            f[4]=q1.x; f[5]=q1.y; f[6]=q1.z; f[7]=q1.w;
            f[8]=q2.x; f[9]=q2.y; f[10]=q2.z; f[11]=q2.w;
            f[12]=q3.x; f[13]=q3.y; f[14]=q3.z; f[15]=q3.w;
        }
        while (cur >= 0) {
            const int nxt = next();
            float g[16];
            if (nxt >= 0) {
                const float* p = df + nxt * NDF + dim0;
                const float4 q0 = ((const float4*)p)[0], q1 = ((const float4*)p)[1];
                const float4 q2 = ((const float4*)p)[2], q3 = ((const float4*)p)[3];
                g[0]=q0.x; g[1]=q0.y; g[2]=q0.z; g[3]=q0.w;
                g[4]=q1.x; g[5]=q1.y; g[6]=q1.z; g[7]=q1.w;
                g[8]=q2.x; g[9]=q2.y; g[10]=q2.z; g[11]=q2.w;
                g[12]=q3.x; g[13]=q3.y; g[14]=q3.z; g[15]=q3.w;
            }
            const float c2 = 1.0f / (nf + 1.0f);
            const float c1 = nf * c2;
            const float c12 = c1 * c2;
#pragma unroll
            for (int j = 0; j < 16; ++j) {
                m[j] = m[j] * c1 + f[j] * c2;     // == f when nf==0
                const float a = f[j] - m[j];
                v[j] = v[j] * c1 + a * a * c12;
            }
            nf += 1.0f;
#pragma unroll
            for (int j = 0; j < 16; ++j) f[j] = g[j];
            cur = nxt;
        }
    }
    __syncthreads();   // bmap reads done before staging overwrites (LDS union!)

    // single staging round: linear cols (A=-2*fc_t*var, B=fc) | quad (A=var, B=fc^2)
    {
        float4 l0, l1, l2, l3;
        l0.x=-2.f*fcq[0]*v[0];  l0.y=-2.f*fcq[1]*v[1];  l0.z=-2.f*fcq[2]*v[2];  l0.w=-2.f*fcq[3]*v[3];
        l1.x=-2.f*fcq[4]*v[4];  l1.y=-2.f*fcq[5]*v[5];  l1.z=-2.f*fcq[6]*v[6];  l1.w=-2.f*fcq[7]*v[7];
        l2.x=-2.f*fcq[8]*v[8];  l2.y=-2.f*fcq[9]*v[9];  l2.z=-2.f*fcq[10]*v[10]; l2.w=-2.f*fcq[11]*v[11];
        l3.x=-2.f*fcq[12]*v[12]; l3.y=-2.f*fcq[13]*v[13]; l3.z=-2.f*fcq[14]*v[14]; l3.w=-2.f*fcq[15]*v[15];
        float4 p0, p1, p2, p3;
        p0.x=v[0];  p0.y=v[1];  p0.z=v[2];  p0.w=v[3];
        p1.x=v[4];  p1.y=v[5];  p1.z=v[6];  p1.w=v[7];
        p2.x=v[8];  p2.y=v[9];  p2.z=v[10]; p2.w=v[11];
        p3.x=v[12]; p3.y=v[13]; p3.z=v[14]; p3.w=v[15];
        float4 s0, s1, s2, s3;
        s0.x=b0.x*b0.x; s0.y=b0.y*b0.y; s0.z=b0.z*b0.z; s0.w=b0.w*b0.w;
        s1.x=b1.x*b1.x; s1.y=b1.y*b1.y; s1.z=b1.z*b1.z; s1.w=b1.w*b1.w;
        s2.x=b2.x*b2.x; s2.y=b2.y*b2.y; s2.z=b2.z*b2.z; s2.w=b2.w*b2.w;
        s3.x=b3.x*b3.x; s3.y=b3.y*b3.y; s3.z=b3.z*b3.z; s3.w=b3.w*b3.w;
        *(uint4*)(arow + ((kbl + 0) ^ sswz)) = pk16(l0, l1);
        *(uint4*)(arow + ((kbl + 16) ^ sswz)) = pk16(l2, l3);
        *(uint4*)(arow + ((kbq + 0) ^ sswz)) = pk16(p0, p1);
        *(uint4*)(arow + ((kbq + 16) ^ sswz)) = pk16(p2, p3);
        *(uint4*)(brow + ((kbl + 0) ^ sswz)) = pk16(b0, b1);
        *(uint4*)(brow + ((kbl + 16) ^ sswz)) = pk16(b2, b3);
        *(uint4*)(brow + ((kbq + 0) ^ sswz)) = pk16(s0, s1);
        *(uint4*)(brow + ((kbq + 16) ^ sswz)) = pk16(s2, s3);
    }
    __syncthreads();
    mma_step(0); mma_step(64); mma_step(128); mma_step(192);

    float* base = Rp + z * (NCLS * NCLS) + (bm * 64) * NCLS + bn * 64;
#pragma unroll
    for (int mi = 0; mi < 2; ++mi)
#pragma unroll
        for (int ni = 0; ni < 2; ++ni)
#pragma unroll
            for (int r2 = 0; r2 < 4; ++r2)
                base[(wm + mi * 16 + (lane >> 4) * 4 + r2) * NCLS + wn + ni * 16 + fr] =
                    acc[mi][ni][r2];
}

// ---------------------------------------------------------------------------
// Kernel 2: grid 256 x 256. Block (bm=bid>>3, bn=bid&7): out rows bm*32..+32,
// cols bn*32..+32. Full K=512 staged once (64KB LDS), 16 MFMA/wave (2 chains),
// fused epilogue: out = s1 - bias1[b] + 0.5*ALP*(sum_z Rz[t,c] - sum_z Rz[t,t]).
__global__ __launch_bounds__(256, 2) void k2_s1_out(const float* __restrict__ df,
                                                    const int* __restrict__ gt,
                                                    const float* __restrict__ fc,
                                                    const float* __restrict__ Rp,
                                                    const float* __restrict__ bias1,
                                                    float* __restrict__ out) {
    __shared__ alignas(16) char A[32 * 1024];   // 32 rows x 512 bf16 (1KB rows)
    __shared__ alignas(16) char B[32 * 1024];

    const int tid = threadIdx.x;
    const int bn = blockIdx.x & 7, bm = blockIdx.x >> 3;

    // staging: row = tid>>3 (0..31), kc = tid&7 -> 64 contiguous dims (16 float4)
    const int row = tid >> 3, kc = tid & 7;
    const float* Ag = df + (bm * 32 + row) * NDF + kc * 64;
    const float* Bg = fc + (bn * 32 + row) * NDF + kc * 64;
    float4 a[16], b[16];
#pragma unroll
    for (int i = 0; i < 16; ++i) a[i] = ((const float4*)Ag)[i];
#pragma unroll
    for (int i = 0; i < 16; ++i) b[i] = ((const float4*)Bg)[i];
    const int swz = (row & 7) << 4;
    char* ar = A + row * 1024;
    char* br = B + row * 1024;
#pragma unroll
    for (int i = 0; i < 8; ++i)
        *(uint4*)(ar + ((kc * 128 + i * 16) ^ swz)) = pk16(a[2 * i], a[2 * i + 1]);
#pragma unroll
    for (int i = 0; i < 8; ++i)
        *(uint4*)(br + ((kc * 128 + i * 16) ^ swz)) = pk16(b[2 * i], b[2 * i + 1]);
    __syncthreads();

    // MFMA: wave quadrant (wm,wn) in {0,16}^2; 16 k-steps, 2 independent chains
    const int lane = tid & 63;
    const int wv = tid >> 6;
    const int wm = (wv >> 1) * 16, wn = (wv & 1) * 16;
    const int fr = lane & 15;
    const int fkb = (lane >> 4) * 16;
    const int fswz = (fr & 7) << 4;
    f32x4 accE = 0.f, accO = 0.f;
#pragma unroll
    for (int s = 0; s < 16; s += 2) {
        const int kb0 = (s * 64 + fkb) ^ fswz;
        const int kb1 = ((s + 1) * 64 + fkb) ^ fswz;
        const bf16x8 aF0 = *(const bf16x8*)(A + (wm + fr) * 1024 + kb0);
        const bf16x8 bF0 = *(const bf16x8*)(B + (wn + fr) * 1024 + kb0);
        const bf16x8 aF1 = *(const bf16x8*)(A + (wm + fr) * 1024 + kb1);
        const bf16x8 bF1 = *(const bf16x8*)(B + (wn + fr) * 1024 + kb1);
        accE = __builtin_amdgcn_mfma_f32_16x16x32_bf16(aF0, bF0, accE, 0, 0, 0);
        accO = __builtin_amdgcn_mfma_f32_16x16x32_bf16(aF1, bF1, accO, 0, 0, 0);
    }

    // fused epilogue: C row = bm*32+wm+(lane>>4)*4+r, col = bn*32+wn+fr
    const int colg = bn * 32 + wn + fr;
#pragma unroll
    for (int r = 0; r < 4; ++r) {
        const int bg = bm * 32 + wm + (lane >> 4) * 4 + r;   // global row (sample)
        const int t = gt[bg];                                 // broadcast per 16 lanes
        float vR = 0.f, vtt = 0.f;
#pragma unroll
        for (int z = 0; z < 8; ++z) {
            const float* rp = Rp + z * (NCLS * NCLS) + t * NCLS;
            vR += rp[colg];
            vtt += rp[t];
        }
        const float v1 = accE[r] + accO[r] - bias1[bg];
        out[bg * NCLS + colg] = v1 + 0.5f * ALP * (vR - vtt);
    }
}

// ---------------------------------------------------------------------------
extern "C" void kernel_launch(void* const* d_in, const int* in_sizes, int n_in,
                              void* d_out, int out_size, void* d_ws, size_t ws_size,
                              hipStream_t stream) {
    const float* df = (const float*)d_in[0];
    const int* gt = (const int*)d_in[1];
    const float* fc = (const float*)d_in[2];
    float* out = (float*)d_out;

    float* ws = (float*)d_ws;
    float* Rp = ws;                            // 8*NCLS*NCLS = 524,288 f (2 MB)
    float* bias1 = Rp + 8 * NCLS * NCLS;       // 1024 f

    k1_R_bias<<<384, 256, 0, stream>>>(df, gt, fc, Rp, bias1);
    k2_s1_out<<<256, 256, 0, stream>>>(df, gt, fc, Rp, bias1, out);
}